// Round 1
// baseline (9906.435 us; speedup 1.0000x reference)
//
#include <hip/hip_runtime.h>
#include <math.h>

#define T_SEQ 2048
#define HID   64
#define GATES 256
#define CHUNK 64

__device__ __forceinline__ float sigmoid_(float x) {
    return 1.0f / (1.0f + __expf(-x));
}
__device__ __forceinline__ float tanh_(float x) {
    float e = __expf(2.0f * x);
    return 1.0f - 2.0f / (e + 1.0f);
}

// One LSTM layer over the whole sequence.
// grid = 256 blocks (1 per batch sample), block = 256 threads (1 per gate row).
// in:  [B, T, IN_DIM] (x for layer 0, h-sequence buffer for layers >= 1)
// out: [B, T, HID]   (may alias `in` for layers >= 1: per-chunk rows are fully
//                     read into LDS before they are overwritten, per-sample
//                     blocks are disjoint)
template <int IN_DIM>
__global__ __launch_bounds__(256, 1)
void lstm_layer_kernel(const float* __restrict__ in,
                       const float* __restrict__ W_ih,   // [GATES, IN_DIM]
                       const float* __restrict__ W_hh,   // [GATES, HID]
                       const float* __restrict__ b_ih,   // [GATES]
                       const float* __restrict__ b_hh,   // [GATES]
                       float* __restrict__ out)
{
    __shared__ float s_in[CHUNK][HID];     // staged input rows (zero-padded cols >= IN_DIM)
    __shared__ float s_xg[CHUNK][GATES];   // input-GEMM results for current chunk
    __shared__ float s_act[GATES];         // activated gates for current step
    __shared__ float s_h[HID];             // current hidden state (block-wide)

    const int g = threadIdx.x;             // gate row 0..255; gate type = g>>6 (i,f,g,o)
    const int s = blockIdx.x;              // batch sample

    // ---- load weight rows into registers (compile-time indexed -> stays in VGPRs)
    float w_ih[HID];
    float w_hh[HID];
#pragma unroll
    for (int k = 0; k < HID; ++k)
        w_ih[k] = (k < IN_DIM) ? W_ih[g * IN_DIM + k] : 0.0f;
#pragma unroll
    for (int k4 = 0; k4 < HID / 4; ++k4) {
        float4 w = *reinterpret_cast<const float4*>(&W_hh[g * HID + k4 * 4]);
        w_hh[k4 * 4 + 0] = w.x;
        w_hh[k4 * 4 + 1] = w.y;
        w_hh[k4 * 4 + 2] = w.z;
        w_hh[k4 * 4 + 3] = w.w;
    }
    const float bias = b_ih[g] + b_hh[g];

    // ---- init: zero s_in (padding cols stay 0 forever), h0 = c0 = 0
    for (int i = g; i < CHUNK * HID; i += 256) (&s_in[0][0])[i] = 0.0f;
    if (g < HID) s_h[g] = 0.0f;
    float c = 0.0f;  // cell state, live in wave-0 threads (g < 64)
    __syncthreads();

    const float* in_s  = in  + (size_t)s * T_SEQ * IN_DIM;
    float*       out_s = out + (size_t)s * T_SEQ * HID;

    for (int t0 = 0; t0 < T_SEQ; t0 += CHUNK) {
        // ---- stage CHUNK input rows into LDS (coalesced); safe without a
        // leading barrier: the previous chunk's recurrence barriers guarantee
        // every thread has finished the previous GEMM phase (last s_in reader).
        for (int i = g; i < CHUNK * IN_DIM; i += 256) {
            int t = i / IN_DIM;
            int k = i - t * IN_DIM;
            s_in[t][k] = in_s[(size_t)t0 * IN_DIM + i];
        }
        __syncthreads();

        // ---- input GEMM phase: xg[t][g] = bias + dot(in_row[t], W_ih[g])
        // (only thread g ever reads s_xg[*][g] -> no barrier needed for s_xg)
#pragma unroll 2
        for (int t = 0; t < CHUNK; ++t) {
            float a0 = bias, a1 = 0.0f, a2 = 0.0f, a3 = 0.0f;
#pragma unroll
            for (int k4 = 0; k4 < HID / 4; ++k4) {
                float4 u = *reinterpret_cast<const float4*>(&s_in[t][k4 * 4]);
                a0 = fmaf(w_ih[k4 * 4 + 0], u.x, a0);
                a1 = fmaf(w_ih[k4 * 4 + 1], u.y, a1);
                a2 = fmaf(w_ih[k4 * 4 + 2], u.z, a2);
                a3 = fmaf(w_ih[k4 * 4 + 3], u.w, a3);
            }
            s_xg[t][g] = (a0 + a1) + (a2 + a3);
        }

        // ---- recurrence over the chunk
        for (int tt = 0; tt < CHUNK; ++tt) {
            float a0 = s_xg[tt][g], a1 = 0.0f, a2 = 0.0f, a3 = 0.0f;
#pragma unroll
            for (int k4 = 0; k4 < HID / 4; ++k4) {
                float4 u = *reinterpret_cast<const float4*>(&s_h[k4 * 4]);  // uniform broadcast
                a0 = fmaf(w_hh[k4 * 4 + 0], u.x, a0);
                a1 = fmaf(w_hh[k4 * 4 + 1], u.y, a1);
                a2 = fmaf(w_hh[k4 * 4 + 2], u.z, a2);
                a3 = fmaf(w_hh[k4 * 4 + 3], u.w, a3);
            }
            float pre = (a0 + a1) + (a2 + a3);

            // gate type is wave-uniform: wave0=i, wave1=f, wave2=g(tanh), wave3=o
            float a = ((g >> 6) == 2) ? tanh_(pre) : sigmoid_(pre);
            s_act[g] = a;
            __syncthreads();

            if (g < HID) {
                float i_ = s_act[g];
                float f_ = s_act[64 + g];
                float g_ = s_act[128 + g];
                float o_ = s_act[192 + g];
                c = f_ * c + i_ * g_;
                float h = o_ * tanh_(c);
                s_h[g] = h;
                out_s[(size_t)(t0 + tt) * HID + g] = h;  // fire-and-forget store
            }
            __syncthreads();
        }
    }
}

// MLP head: features = gelu(last @ Wl^T + bl); out = relu(features @ Wo^T + bo)
// d_out layout: out[256*4] first, then features[256*128].
__global__ __launch_bounds__(128)
void head_kernel(const float* __restrict__ h_buf,  // [B, T, HID]
                 const float* __restrict__ Wl,     // [128, 64]
                 const float* __restrict__ bl,     // [128]
                 const float* __restrict__ Wo,     // [4, 128]
                 const float* __restrict__ bo,     // [4]
                 float* __restrict__ d_out)
{
    __shared__ float s_last[HID];
    __shared__ float s_feat[128];
    const int s = blockIdx.x;
    const int j = threadIdx.x;

    if (j < HID)
        s_last[j] = h_buf[(size_t)s * T_SEQ * HID + (size_t)(T_SEQ - 1) * HID + j];
    __syncthreads();

    float acc = bl[j];
#pragma unroll
    for (int k = 0; k < HID; ++k)
        acc = fmaf(s_last[k], Wl[j * HID + k], acc);
    // exact GELU: 0.5 * x * (1 + erf(x / sqrt(2)))
    float f = 0.5f * acc * (1.0f + erff(acc * 0.70710678118654752440f));
    d_out[256 * 4 + s * 128 + j] = f;
    s_feat[j] = f;
    __syncthreads();

    if (j < 4) {
        float a = bo[j];
#pragma unroll
        for (int k = 0; k < 128; ++k)
            a = fmaf(s_feat[k], Wo[j * 128 + k], a);
        d_out[s * 4 + j] = fmaxf(a, 0.0f);
    }
}

extern "C" void kernel_launch(void* const* d_in, const int* in_sizes, int n_in,
                              void* d_out, int out_size, void* d_ws, size_t ws_size,
                              hipStream_t stream)
{
    const float* x         = (const float*)d_in[0];  // [256, 2048, 45]
    const float* W_ih0     = (const float*)d_in[1];  // [256, 45]
    const float* W_ih_rest = (const float*)d_in[2];  // [4, 256, 64]
    const float* W_hh      = (const float*)d_in[3];  // [5, 256, 64]
    const float* b_ih      = (const float*)d_in[4];  // [5, 256]
    const float* b_hh      = (const float*)d_in[5];  // [5, 256]
    const float* Wl        = (const float*)d_in[6];  // [128, 64]
    const float* bl        = (const float*)d_in[7];  // [128]
    const float* Wo        = (const float*)d_in[8];  // [4, 128]
    const float* bo        = (const float*)d_in[9];  // [4]

    float* h_buf = (float*)d_ws;  // [256, 2048, 64] fp32 = 134 MB

    lstm_layer_kernel<45><<<256, 256, 0, stream>>>(
        x, W_ih0, W_hh, b_ih, b_hh, h_buf);
    for (int l = 1; l < 5; ++l) {
        lstm_layer_kernel<64><<<256, 256, 0, stream>>>(
            h_buf,
            W_ih_rest + (size_t)(l - 1) * GATES * HID,
            W_hh + (size_t)l * GATES * HID,
            b_ih + (size_t)l * GATES,
            b_hh + (size_t)l * GATES,
            h_buf);
    }
    head_kernel<<<256, 128, 0, stream>>>(h_buf, Wl, bl, Wo, bo, (float*)d_out);
}